// Round 9
// baseline (637.860 us; speedup 1.0000x reference)
//
#include <hip/hip_runtime.h>

#define IN_CH 65
#define HID 64
#define BN 64        // nodes per bucket
#define NB 1563      // ceil(100000 / BN)
#define CAP 2560     // pair slots per bucket (mean 2048, +11 sigma) == 5*512
#define SCAP 2432    // LDS sorted capacity (mean 2048, +8.5 sigma)
#define GT 2         // gemm tiles per prep block (2 x 256-thr sub-blocks)
#define PTPB 512     // prep threads per block
#define SEPB 8192    // scatter edges per prep block
#define SEPT (SEPB / PTPB)  // 16 edges per thread
#define WSTR 132     // fallback k1 LDS W row stride

static inline size_t align16(size_t v) { return (v + 15) & ~(size_t)15; }

__device__ inline ushort f2bf(float f) {
    uint u = __float_as_uint(f);
    return (ushort)((u + 0x7FFF + ((u >> 16) & 1)) >> 16);  // RNE
}

// ---------------------------------------------------------------------------
// prep v3: fused k1both + scatter, role pattern {G,G,S} by blockIdx%3.
// vs R8: the scatter role is now LDS-FREE (per-edge global atomicAdd on cnt
// + direct pair write). R8 showed occupancy was not the limiter — G and S
// contend on the per-CU LDS pipe (S: 2 LDS atomics/edge + 3 barriers; G:
// ds_read-bound GEMM). LDS-free S puts the roles on disjoint pipes
// (G: VALU/LDS, S: VMEM/atomic), which is the overlap-to-max regime.
// Atomic contention: 3.2M atomics / 1563 counters ~ 2048/counter, parallel
// across L2 channels — microseconds.
// cnt zeroed by a preceding hipMemsetAsync node.
// ---------------------------------------------------------------------------
__global__ __launch_bounds__(PTPB) void prep(const float* __restrict__ x,
                                             const float* __restrict__ W_rel,
                                             const float* __restrict__ W_root,
                                             const float* __restrict__ b_rel,
                                             ushort* __restrict__ y16,
                                             float* __restrict__ out,
                                             const int* __restrict__ ei,
                                             const float* __restrict__ ew,
                                             int* __restrict__ cnt,
                                             int2* __restrict__ pairs,
                                             int nNodes, int nTiles, int E) {
    __shared__ __align__(16) char smem[3 * 65 * 68 * 4];  // 53040 B (G role)
    const int bid = blockIdx.x;
    const int s3 = bid / 3, r3 = bid - s3 * 3;
    const int tid = threadIdx.x;

    if (r3 != 2) {
        // ---------------- GEMM role (unchanged from R8) -------------------
        const int gblk = s3 * 2 + r3;
        const int sub = tid >> 8;        // 0/1 sub-block
        const int t256 = tid & 255;
        const int tile = gblk * GT + sub;
        float* xsT = (float*)smem + sub * (65 * 68);   // per-sub x tile
        float* ws  = (float*)smem + 2 * (65 * 68);     // SHARED W buffer
        const int tx = t256 & 15;        // 16 ch-groups (4 ch each)
        const int ty = t256 >> 4;        // 16 node-groups (4 nodes each)
        const long nodeBase = (long)tile * 64;
        const int nValid = (int)min((long)64, (long)nNodes - nodeBase);

        // ws staged by ALL 512 threads (once); xsT by each sub's 256
        for (int f = tid; f < HID * IN_CH; f += PTPB) {
            const int j = f / IN_CH, c = f - j * IN_CH;
            ws[c * 68 + j] = W_rel[f];
        }
        const float* xsrc = x + nodeBase * IN_CH;
        for (int f = t256; f < 64 * IN_CH; f += 256) {
            const int node = f / IN_CH, k = f - node * IN_CH;
            xsT[k * 68 + node] = (node < nValid) ? xsrc[f] : 0.f;
        }
        __syncthreads();

        const int r0 = ty * 4;
        const int c0 = tx * 4;

        // ---- phase 1: y16 = bf16(x @ W_rel.T) ----
        {
            float acc[4][4];
#pragma unroll
            for (int i = 0; i < 4; ++i)
#pragma unroll
                for (int j = 0; j < 4; ++j) acc[i][j] = 0.f;

            for (int k = 0; k < IN_CH; ++k) {
                const float4 a4 = *(const float4*)&xsT[k * 68 + r0];
                const float4 b4 = *(const float4*)&ws[k * 68 + c0];
                const float aa[4] = {a4.x, a4.y, a4.z, a4.w};
                const float bb[4] = {b4.x, b4.y, b4.z, b4.w};
#pragma unroll
                for (int i = 0; i < 4; ++i)
#pragma unroll
                    for (int j = 0; j < 4; ++j) acc[i][j] += aa[i] * bb[j];
            }
#pragma unroll
            for (int i = 0; i < 4; ++i) {
                const long node = nodeBase + r0 + i;
                if (node >= nNodes) break;
                uint2 pk;
                pk.x = (uint)f2bf(acc[i][0]) | ((uint)f2bf(acc[i][1]) << 16);
                pk.y = (uint)f2bf(acc[i][2]) | ((uint)f2bf(acc[i][3]) << 16);
                *(uint2*)&y16[node * HID + c0] = pk;
            }
        }
        __syncthreads();  // both subs done with ws = W_rel

        for (int f = tid; f < HID * IN_CH; f += PTPB) {
            const int j = f / IN_CH, c = f - j * IN_CH;
            ws[c * 68 + j] = W_root[f];
        }
        __syncthreads();

        // ---- phase 2: out = x @ W_root.T + b_rel ----
        {
            const float4 bb4 = *(const float4*)&b_rel[c0];
            float acc[4][4];
#pragma unroll
            for (int i = 0; i < 4; ++i) {
                acc[i][0] = bb4.x; acc[i][1] = bb4.y;
                acc[i][2] = bb4.z; acc[i][3] = bb4.w;
            }
            for (int k = 0; k < IN_CH; ++k) {
                const float4 a4 = *(const float4*)&xsT[k * 68 + r0];
                const float4 b4 = *(const float4*)&ws[k * 68 + c0];
                const float aa[4] = {a4.x, a4.y, a4.z, a4.w};
                const float bb[4] = {b4.x, b4.y, b4.z, b4.w};
#pragma unroll
                for (int i = 0; i < 4; ++i)
#pragma unroll
                    for (int j = 0; j < 4; ++j) acc[i][j] += aa[i] * bb[j];
            }
#pragma unroll
            for (int i = 0; i < 4; ++i) {
                const long node = nodeBase + r0 + i;
                if (node >= nNodes) break;
                *(float4*)&out[node * HID + c0] =
                    make_float4(acc[i][0], acc[i][1], acc[i][2], acc[i][3]);
            }
        }
    } else {
        // ---------------- scatter role: LDS-free, barrier-free ------------
        const long e0 = (long)s3 * SEPB;
        const int n = (int)min((long)SEPB, (long)E - e0);
#pragma unroll
        for (int k = 0; k < SEPT; ++k) {
            const int i = tid + k * PTPB;   // coalesced across the block
            if (i < n) {
                const int dst = ei[(long)E + e0 + i];
                const int src = ei[e0 + i];
                const float w = ew[e0 + i];
                const int b = dst >> 6;
                const int p = atomicAdd(&cnt[b], 1);
                if (p < CAP)
                    pairs[(size_t)b * CAP + p] =
                        make_int2((src << 7) | ((dst & (BN - 1)) << 25),
                                  __float_as_int(w));
            }
        }
    }
}

// ---------------------------------------------------------------------------
// aggregateS16: EXACT R4/R6 version (measured 59-60 us, occ ~61%, VGPR 24).
// ---------------------------------------------------------------------------
__global__ __launch_bounds__(512) void aggregateS16(const int2* __restrict__ pairs,
                                                    const int* __restrict__ cnt,
                                                    const ushort* __restrict__ y16,
                                                    float* __restrict__ out, int N) {
    __shared__ int2 sorted[SCAP];  // 19.5 KB
    __shared__ int sH[BN];
    __shared__ int soff[BN + 1];
    __shared__ int scur[BN];
    const int tid = threadIdx.x;
    const int lane = tid & 63;
    const int wvid = tid >> 6;     // 0..7
    const int half = lane >> 5;
    const uint lane4 = (lane & 31) * 4;
    const int b = blockIdx.x;

    if (tid < BN) { sH[tid] = 0; scur[tid] = 0; }

    const int m = min(cnt[b], CAP);
    const int2* pb = pairs + (size_t)b * CAP;

    // single global pass: register-cache the <=5 pairs (CAP = 5*512)
    int2 pv[5];
#pragma unroll
    for (int kk = 0; kk < 5; ++kk) {
        const int i = tid + kk * 512;
        if (i < m) pv[kk] = pb[i];
    }
    __syncthreads();  // sH zeroed

#pragma unroll
    for (int kk = 0; kk < 5; ++kk) {
        const int i = tid + kk * 512;
        if (i < m) atomicAdd(&sH[(uint)pv[kk].x >> 25], 1);
    }
    __syncthreads();

    for (int off = 1; off < BN; off <<= 1) {
        int v = 0;
        if (tid < BN) {
            v = sH[tid];
            if (tid >= off) v += sH[tid - off];
        }
        __syncthreads();
        if (tid < BN) sH[tid] = v;
        __syncthreads();
    }
    if (tid < BN) soff[tid + 1] = sH[tid];
    if (tid == 0) soff[0] = 0;
    __syncthreads();

    // counting-sort scatter into LDS from registers
#pragma unroll
    for (int kk = 0; kk < 5; ++kk) {
        const int i = tid + kk * 512;
        if (i < m) {
            const int d = (uint)pv[kk].x >> 25;
            const int slot = soff[d] + atomicAdd(&scur[d], 1);
            if (slot < SCAP) sorted[slot] = make_int2(pv[kk].x & 0x00FFFF80, pv[kk].y);
        }
    }
    __syncthreads();

    const char* yb = (const char*)y16;
    const long nodeBase = (long)b * BN;
    for (int nl = wvid; nl < BN; nl += 8) {
        const long node = nodeBase + nl;
        if (node >= N) break;
        const int kbeg = min(soff[nl], SCAP);
        const int kend = min(soff[nl + 1], SCAP);
        // prefetch the RMW operand early; its latency hides under the gathers
        float2* o = (float2*)(out + node * HID) + (lane & 31);
        const float2 cur = *o;
        float ax = 0.f, ay = 0.f;
        int k = kbeg + half;
        for (; k + 14 < kend; k += 16) {
            int2 pp[8];
#pragma unroll
            for (int j = 0; j < 8; ++j) pp[j] = sorted[k + 2 * j];
            uint qq[8];
#pragma unroll
            for (int j = 0; j < 8; ++j)
                qq[j] = *(const uint*)(yb + (uint)pp[j].x + lane4);
#pragma unroll
            for (int j = 0; j < 8; ++j) {
                const float w = __int_as_float(pp[j].y);
                ax += w * __uint_as_float(qq[j] << 16);
                ay += w * __uint_as_float(qq[j] & 0xFFFF0000u);
            }
        }
        for (; k + 6 < kend; k += 8) {
            const int2 p0 = sorted[k],     p1 = sorted[k + 2];
            const int2 p2 = sorted[k + 4], p3 = sorted[k + 6];
            const uint q0 = *(const uint*)(yb + (uint)p0.x + lane4);
            const uint q1 = *(const uint*)(yb + (uint)p1.x + lane4);
            const uint q2 = *(const uint*)(yb + (uint)p2.x + lane4);
            const uint q3 = *(const uint*)(yb + (uint)p3.x + lane4);
            const float w0 = __int_as_float(p0.y), w1 = __int_as_float(p1.y);
            const float w2 = __int_as_float(p2.y), w3 = __int_as_float(p3.y);
            ax += w0 * __uint_as_float(q0 << 16);
            ay += w0 * __uint_as_float(q0 & 0xFFFF0000u);
            ax += w1 * __uint_as_float(q1 << 16);
            ay += w1 * __uint_as_float(q1 & 0xFFFF0000u);
            ax += w2 * __uint_as_float(q2 << 16);
            ay += w2 * __uint_as_float(q2 & 0xFFFF0000u);
            ax += w3 * __uint_as_float(q3 << 16);
            ay += w3 * __uint_as_float(q3 & 0xFFFF0000u);
        }
        for (; k < kend; k += 2) {
            const int2 p = sorted[k];
            const uint q = *(const uint*)(yb + (uint)p.x + lane4);
            const float w = __int_as_float(p.y);
            ax += w * __uint_as_float(q << 16);
            ay += w * __uint_as_float(q & 0xFFFF0000u);
        }
        ax += __shfl_xor(ax, 32);
        ay += __shfl_xor(ay, 32);
        if (half == 0) {
            *o = make_float2(cur.x + ax, cur.y + ay);
        }
    }
}

// ---------------------------------------------------------------------------
// Fallback path: original full k1 + atomic scatter.
// ---------------------------------------------------------------------------
__global__ __launch_bounds__(256) void k1_full(const float* __restrict__ x,
                                               const float* __restrict__ W_rel,
                                               const float* __restrict__ b_rel,
                                               const float* __restrict__ W_root,
                                               ushort* __restrict__ y16,
                                               float* __restrict__ out,
                                               int nNodes) {
    __shared__ float xs[64 * IN_CH];
    __shared__ float ws[IN_CH * WSTR];
    const int tid = threadIdx.x;
    const int tx = tid & 15;
    const int ty = tid >> 4;
    const long nodeBase = (long)blockIdx.x * 64;
    const int nValid = min(64, nNodes - (int)nodeBase);
    const int nx = nValid * IN_CH;

    for (int f = tid; f < HID * IN_CH; f += 256) {
        const int j = f / IN_CH, c = f - j * IN_CH;
        ws[c * WSTR + j] = W_rel[f];
    }
    for (int f = tid; f < HID * IN_CH; f += 256) {
        const int j = f / IN_CH, c = f - j * IN_CH;
        ws[c * WSTR + HID + j] = W_root[f];
    }
    const float* xsrc = x + nodeBase * IN_CH;
    for (int i = tid; i < 64 * IN_CH; i += 256) xs[i] = (i < nx) ? xsrc[i] : 0.f;
    __syncthreads();

    float acc[4][8];
#pragma unroll
    for (int i = 0; i < 4; ++i)
#pragma unroll
        for (int j = 0; j < 8; ++j) acc[i][j] = 0.f;

    const int r0 = ty * 4;
    const int c0 = tx * 8;
    for (int k = 0; k < IN_CH; ++k) {
        float aa[4] = {xs[(r0 + 0) * IN_CH + k], xs[(r0 + 1) * IN_CH + k],
                       xs[(r0 + 2) * IN_CH + k], xs[(r0 + 3) * IN_CH + k]};
        float4 b0 = *(const float4*)&ws[k * WSTR + c0];
        float4 b1 = *(const float4*)&ws[k * WSTR + c0 + 4];
        float bb[8] = {b0.x, b0.y, b0.z, b0.w, b1.x, b1.y, b1.z, b1.w};
#pragma unroll
        for (int i = 0; i < 4; ++i)
#pragma unroll
            for (int j = 0; j < 8; ++j) acc[i][j] += aa[i] * bb[j];
    }

    if (c0 >= HID) {
        const int h0 = c0 - HID;
        float4 bb0 = *(const float4*)&b_rel[h0];
        float4 bb1 = *(const float4*)&b_rel[h0 + 4];
        float bv[8] = {bb0.x, bb0.y, bb0.z, bb0.w, bb1.x, bb1.y, bb1.z, bb1.w};
#pragma unroll
        for (int i = 0; i < 4; ++i)
#pragma unroll
            for (int j = 0; j < 8; ++j) acc[i][j] += bv[j];
    }

#pragma unroll
    for (int i = 0; i < 4; ++i) {
        const long node = nodeBase + r0 + i;
        if (node >= nNodes) break;
        if (c0 < HID) {
            uint4 pk;
            pk.x = (uint)f2bf(acc[i][0]) | ((uint)f2bf(acc[i][1]) << 16);
            pk.y = (uint)f2bf(acc[i][2]) | ((uint)f2bf(acc[i][3]) << 16);
            pk.z = (uint)f2bf(acc[i][4]) | ((uint)f2bf(acc[i][5]) << 16);
            pk.w = (uint)f2bf(acc[i][6]) | ((uint)f2bf(acc[i][7]) << 16);
            *(uint4*)&y16[node * HID + c0] = pk;
        } else {
            float* dst = out + node * HID + (c0 - HID);
            *(float4*)(dst + 0) = make_float4(acc[i][0], acc[i][1], acc[i][2], acc[i][3]);
            *(float4*)(dst + 4) = make_float4(acc[i][4], acc[i][5], acc[i][6], acc[i][7]);
        }
    }
}

__global__ __launch_bounds__(256) void k2_atomic16(const int* __restrict__ ei,
                                                   const float* __restrict__ ew,
                                                   const ushort* __restrict__ y16,
                                                   float* __restrict__ out, int E) {
    const long t = (long)blockIdx.x * 256 + threadIdx.x;
    const long e = t >> 4;
    const int r = (int)(t & 15);
    if (e >= E) return;
    const int src = ei[e];
    const int dst = ei[(long)E + e];
    const float w = ew[e];
    const uint2 q = ((const uint2*)y16)[(size_t)src * 16 + r];
    float* o = out + (size_t)dst * HID + r * 4;
    unsafeAtomicAdd(o + 0, w * __uint_as_float(q.x << 16));
    unsafeAtomicAdd(o + 1, w * __uint_as_float(q.x & 0xFFFF0000u));
    unsafeAtomicAdd(o + 2, w * __uint_as_float(q.y << 16));
    unsafeAtomicAdd(o + 3, w * __uint_as_float(q.y & 0xFFFF0000u));
}

extern "C" void kernel_launch(void* const* d_in, const int* in_sizes, int n_in,
                              void* d_out, int out_size, void* d_ws, size_t ws_size,
                              hipStream_t stream) {
    const float* x      = (const float*)d_in[0];
    const int*   ei     = (const int*)d_in[1];
    const float* ew     = (const float*)d_in[2];
    const float* W_rel  = (const float*)d_in[3];
    const float* b_rel  = (const float*)d_in[4];
    const float* W_root = (const float*)d_in[5];
    float* out = (float*)d_out;

    const int N = in_sizes[0] / IN_CH;  // 100000
    const int E = in_sizes[2];          // 3200000

    char* base = (char*)d_ws;
    const size_t oY     = 0;
    const size_t oPairs = align16((size_t)N * HID * 2);
    const size_t oCnt   = oPairs + align16((size_t)NB * CAP * 8);
    const size_t need   = oCnt + (size_t)NB * 4;

    ushort* y16 = (ushort*)(base + oY);
    const int nTiles = (N + 63) / 64;   // 64-node GEMM tiles

    const bool fits = (ws_size >= need) && (N <= (1 << 17)) &&
                      ((size_t)NB * BN >= (size_t)N) && ((long)E <= (long)N * 33);

    if (fits) {
        int2* pairs = (int2*)(base + oPairs);
        int*  cnt   = (int*)(base + oCnt);

        hipMemsetAsync(cnt, 0, (size_t)NB * sizeof(int), stream);

        const int gemmBlocks = (nTiles + GT - 1) / GT;            // 782
        const int scatBlocks = (E + SEPB - 1) / SEPB;             // 391
        const int nTrip = max((gemmBlocks + 1) / 2, scatBlocks);  // 391
        const int grid = nTrip * 3;                               // 1173

        prep<<<grid, PTPB, 0, stream>>>(x, W_rel, W_root, b_rel, y16, out,
                                        ei, ew, cnt, pairs, N, nTiles, E);
        aggregateS16<<<NB, 512, 0, stream>>>(pairs, cnt, y16, out, N);
    } else {
        const int nbf = (N + 63) / 64;
        k1_full<<<nbf, 256, 0, stream>>>(x, W_rel, b_rel, W_root, y16, out, N);
        const long thr2 = (long)E * 16;
        k2_atomic16<<<(int)((thr2 + 255) / 256), 256, 0, stream>>>(ei, ew, y16, out, E);
    }
}

// Round 10
// 225.650 us; speedup vs baseline: 2.8268x; 2.8268x over previous
//
#include <hip/hip_runtime.h>
#include <hip/hip_cooperative_groups.h>

namespace cg = cooperative_groups;

#define IN_CH 65
#define HID 64
#define BN 64        // nodes per bucket
#define NB 1563      // ceil(100000 / BN)
#define CAP 2560     // pair slots per bucket (mean 2048, +11 sigma) == 5*512
#define SCAP 2432    // LDS sorted capacity (mean 2048, +8.5 sigma)
#define GT 2         // gemm tiles per G-unit (2 x 256-thr sub-blocks)
#define PTPB 512     // threads per block
#define SEPB 8192    // scatter edges per S-unit
#define SEPT (SEPB / PTPB)  // 16 edges per thread
#define WSTR 132     // fallback k1 LDS W row stride

static inline size_t align16(size_t v) { return (v + 15) & ~(size_t)15; }

__device__ inline ushort f2bf(float f) {
    uint u = __float_as_uint(f);
    return (ushort)((u + 0x7FFF + ((u >> 16) & 1)) >> 16);  // RNE
}

// ===========================================================================
// fused: entire pipeline in ONE cooperative dispatch.
//   phase 0: grid-stride zero cnt                      -> grid.sync
//   phase A: {G,G,S} unit loop (R8 prep, unit-strided) -> fence + grid.sync
//   phase B: grid-stride agg over 1563 buckets (frozen R4/R6 body)
// 768 persistent blocks (53KB LDS -> 3 blocks/CU). Rationale: kernels sum to
// ~147 us but totals are ~220-226 across all rounds — ~75 us is dispatch
// overhead; this removes 2 of 3 boundaries.
// ===========================================================================
__global__ __launch_bounds__(PTPB) void fused(const float* __restrict__ x,
                                              const float* __restrict__ W_rel,
                                              const float* __restrict__ W_root,
                                              const float* __restrict__ b_rel,
                                              ushort* __restrict__ y16,
                                              float* __restrict__ out,
                                              const int* __restrict__ ei,
                                              const float* __restrict__ ew,
                                              int* __restrict__ cnt,
                                              int2* __restrict__ pairs,
                                              int nNodes, int nTiles, int E,
                                              int NU) {
    __shared__ __align__(16) char smem[3 * 65 * 68 * 4];  // 53040 B union
    cg::grid_group grid = cg::this_grid();
    const int tid = threadIdx.x;
    const int sUnits = (E + SEPB - 1) / SEPB;
    const int gUnits = (nTiles + GT - 1) / GT;

    // ---------------- phase 0: zero cnt --------------------------------
    for (int i = blockIdx.x * PTPB + tid; i < NB; i += gridDim.x * PTPB)
        cnt[i] = 0;
    grid.sync();

    // ---------------- phase A: {G,G,S} units ---------------------------
    for (int u = blockIdx.x; u < NU; u += gridDim.x) {
        const int trip = u / 3, r = u - trip * 3;
        if (r == 2) {
            // ---- scatter unit (R8 LDS-batched body) ----
            if (trip < sUnits) {
                int* lhist = (int*)smem;
                int* lbase = lhist + NB;
                const long e0 = (long)trip * SEPB;
                const int n = (int)min((long)SEPB, (long)E - e0);

                for (int i = tid; i < NB; i += PTPB) lhist[i] = 0;
                __syncthreads();

                int dstv[SEPT], srcv[SEPT];
                float wv[SEPT];
#pragma unroll
                for (int k = 0; k < SEPT; ++k) {
                    const int i = tid + k * PTPB;
                    const bool valid = i < n;
                    dstv[k] = valid ? ei[(long)E + e0 + i] : 0;
                    srcv[k] = valid ? ei[e0 + i] : 0;
                    wv[k]   = valid ? ew[e0 + i] : 0.f;
                    if (valid) atomicAdd(&lhist[dstv[k] >> 6], 1);
                }
                __syncthreads();

                for (int i = tid; i < NB; i += PTPB) {
                    const int c = lhist[i];
                    lbase[i] = c ? atomicAdd(&cnt[i], c) : 0;
                    lhist[i] = 0;  // reuse as local cursor
                }
                __syncthreads();

#pragma unroll
                for (int k = 0; k < SEPT; ++k) {
                    const int i = tid + k * PTPB;
                    if (i < n) {
                        const int b = dstv[k] >> 6;
                        const int p = lbase[b] + atomicAdd(&lhist[b], 1);
                        if (p < CAP)
                            pairs[(size_t)b * CAP + p] =
                                make_int2((srcv[k] << 7) |
                                          ((dstv[k] & (BN - 1)) << 25),
                                          __float_as_int(wv[k]));
                    }
                }
            }
        } else {
            // ---- GEMM unit (R8 shared-ws two-phase body) ----
            const int gblk = trip * 2 + r;
            if (gblk < gUnits) {
                const int sub = tid >> 8;        // 0/1 sub-block
                const int t256 = tid & 255;
                const int tile = gblk * GT + sub;
                float* xsT = (float*)smem + sub * (65 * 68);
                float* ws  = (float*)smem + 2 * (65 * 68);   // shared W
                const int tx = t256 & 15;
                const int ty = t256 >> 4;
                const long nodeBase = (long)tile * 64;
                const int nValid = (int)min((long)64, (long)nNodes - nodeBase);

                for (int f = tid; f < HID * IN_CH; f += PTPB) {
                    const int j = f / IN_CH, c = f - j * IN_CH;
                    ws[c * 68 + j] = W_rel[f];
                }
                const float* xsrc = x + nodeBase * IN_CH;
                for (int f = t256; f < 64 * IN_CH; f += 256) {
                    const int node = f / IN_CH, k = f - node * IN_CH;
                    xsT[k * 68 + node] = (node < nValid) ? xsrc[f] : 0.f;
                }
                __syncthreads();

                const int r0 = ty * 4;
                const int c0 = tx * 4;

                // phase 1: y16 = bf16(x @ W_rel.T)
                {
                    float acc[4][4];
#pragma unroll
                    for (int i = 0; i < 4; ++i)
#pragma unroll
                        for (int j = 0; j < 4; ++j) acc[i][j] = 0.f;

                    for (int k = 0; k < IN_CH; ++k) {
                        const float4 a4 = *(const float4*)&xsT[k * 68 + r0];
                        const float4 b4 = *(const float4*)&ws[k * 68 + c0];
                        const float aa[4] = {a4.x, a4.y, a4.z, a4.w};
                        const float bb[4] = {b4.x, b4.y, b4.z, b4.w};
#pragma unroll
                        for (int i = 0; i < 4; ++i)
#pragma unroll
                            for (int j = 0; j < 4; ++j)
                                acc[i][j] += aa[i] * bb[j];
                    }
#pragma unroll
                    for (int i = 0; i < 4; ++i) {
                        const long node = nodeBase + r0 + i;
                        if (node >= nNodes) break;
                        uint2 pk;
                        pk.x = (uint)f2bf(acc[i][0]) | ((uint)f2bf(acc[i][1]) << 16);
                        pk.y = (uint)f2bf(acc[i][2]) | ((uint)f2bf(acc[i][3]) << 16);
                        *(uint2*)&y16[node * HID + c0] = pk;
                    }
                }
                __syncthreads();  // both subs done with ws = W_rel

                for (int f = tid; f < HID * IN_CH; f += PTPB) {
                    const int j = f / IN_CH, c = f - j * IN_CH;
                    ws[c * 68 + j] = W_root[f];
                }
                __syncthreads();

                // phase 2: out = x @ W_root.T + b_rel
                {
                    const float4 bb4 = *(const float4*)&b_rel[c0];
                    float acc[4][4];
#pragma unroll
                    for (int i = 0; i < 4; ++i) {
                        acc[i][0] = bb4.x; acc[i][1] = bb4.y;
                        acc[i][2] = bb4.z; acc[i][3] = bb4.w;
                    }
                    for (int k = 0; k < IN_CH; ++k) {
                        const float4 a4 = *(const float4*)&xsT[k * 68 + r0];
                        const float4 b4 = *(const float4*)&ws[k * 68 + c0];
                        const float aa[4] = {a4.x, a4.y, a4.z, a4.w};
                        const float bb[4] = {b4.x, b4.y, b4.z, b4.w};
#pragma unroll
                        for (int i = 0; i < 4; ++i)
#pragma unroll
                            for (int j = 0; j < 4; ++j)
                                acc[i][j] += aa[i] * bb[j];
                    }
#pragma unroll
                    for (int i = 0; i < 4; ++i) {
                        const long node = nodeBase + r0 + i;
                        if (node >= nNodes) break;
                        *(float4*)&out[node * HID + c0] =
                            make_float4(acc[i][0], acc[i][1], acc[i][2], acc[i][3]);
                    }
                }
            }
        }
        __syncthreads();  // smem reuse between units
    }

    __threadfence();
    grid.sync();

    // ---------------- phase B: aggregate (frozen R4/R6 body) ------------
    int2* sorted = (int2*)smem;                     // 19456 B
    int*  sH     = (int*)(smem + 19456);
    int*  soff   = sH + BN;
    int*  scur   = soff + BN + 1;
    const int lane = tid & 63;
    const int wvid = tid >> 6;
    const int half = lane >> 5;
    const uint lane4 = (lane & 31) * 4;
    const char* yb = (const char*)y16;

    for (int b = blockIdx.x; b < NB; b += gridDim.x) {
        if (tid < BN) { sH[tid] = 0; scur[tid] = 0; }

        const int m = min(cnt[b], CAP);
        const int2* pb = pairs + (size_t)b * CAP;

        int2 pv[5];
#pragma unroll
        for (int kk = 0; kk < 5; ++kk) {
            const int i = tid + kk * 512;
            if (i < m) pv[kk] = pb[i];
        }
        __syncthreads();  // sH zeroed (and prior bucket's gather complete)

#pragma unroll
        for (int kk = 0; kk < 5; ++kk) {
            const int i = tid + kk * 512;
            if (i < m) atomicAdd(&sH[(uint)pv[kk].x >> 25], 1);
        }
        __syncthreads();

        for (int off = 1; off < BN; off <<= 1) {
            int v = 0;
            if (tid < BN) {
                v = sH[tid];
                if (tid >= off) v += sH[tid - off];
            }
            __syncthreads();
            if (tid < BN) sH[tid] = v;
            __syncthreads();
        }
        if (tid < BN) soff[tid + 1] = sH[tid];
        if (tid == 0) soff[0] = 0;
        __syncthreads();

#pragma unroll
        for (int kk = 0; kk < 5; ++kk) {
            const int i = tid + kk * 512;
            if (i < m) {
                const int d = (uint)pv[kk].x >> 25;
                const int slot = soff[d] + atomicAdd(&scur[d], 1);
                if (slot < SCAP)
                    sorted[slot] = make_int2(pv[kk].x & 0x00FFFF80, pv[kk].y);
            }
        }
        __syncthreads();

        const long nodeBase = (long)b * BN;
        for (int nl = wvid; nl < BN; nl += 8) {
            const long node = nodeBase + nl;
            if (node >= nNodes) break;
            const int kbeg = min(soff[nl], SCAP);
            const int kend = min(soff[nl + 1], SCAP);
            float2* o = (float2*)(out + node * HID) + (lane & 31);
            const float2 cur = *o;
            float ax = 0.f, ay = 0.f;
            int k = kbeg + half;
            for (; k + 14 < kend; k += 16) {
                int2 pp[8];
#pragma unroll
                for (int j = 0; j < 8; ++j) pp[j] = sorted[k + 2 * j];
                uint qq[8];
#pragma unroll
                for (int j = 0; j < 8; ++j)
                    qq[j] = *(const uint*)(yb + (uint)pp[j].x + lane4);
#pragma unroll
                for (int j = 0; j < 8; ++j) {
                    const float w = __int_as_float(pp[j].y);
                    ax += w * __uint_as_float(qq[j] << 16);
                    ay += w * __uint_as_float(qq[j] & 0xFFFF0000u);
                }
            }
            for (; k + 6 < kend; k += 8) {
                const int2 p0 = sorted[k],     p1 = sorted[k + 2];
                const int2 p2 = sorted[k + 4], p3 = sorted[k + 6];
                const uint q0 = *(const uint*)(yb + (uint)p0.x + lane4);
                const uint q1 = *(const uint*)(yb + (uint)p1.x + lane4);
                const uint q2 = *(const uint*)(yb + (uint)p2.x + lane4);
                const uint q3 = *(const uint*)(yb + (uint)p3.x + lane4);
                const float w0 = __int_as_float(p0.y), w1 = __int_as_float(p1.y);
                const float w2 = __int_as_float(p2.y), w3 = __int_as_float(p3.y);
                ax += w0 * __uint_as_float(q0 << 16);
                ay += w0 * __uint_as_float(q0 & 0xFFFF0000u);
                ax += w1 * __uint_as_float(q1 << 16);
                ay += w1 * __uint_as_float(q1 & 0xFFFF0000u);
                ax += w2 * __uint_as_float(q2 << 16);
                ay += w2 * __uint_as_float(q2 & 0xFFFF0000u);
                ax += w3 * __uint_as_float(q3 << 16);
                ay += w3 * __uint_as_float(q3 & 0xFFFF0000u);
            }
            for (; k < kend; k += 2) {
                const int2 p = sorted[k];
                const uint q = *(const uint*)(yb + (uint)p.x + lane4);
                const float w = __int_as_float(p.y);
                ax += w * __uint_as_float(q << 16);
                ay += w * __uint_as_float(q & 0xFFFF0000u);
            }
            ax += __shfl_xor(ax, 32);
            ay += __shfl_xor(ay, 32);
            if (half == 0) {
                *o = make_float2(cur.x + ax, cur.y + ay);
            }
        }
        __syncthreads();  // sorted/soff reuse by next bucket
    }
}

// ===========================================================================
// Fallback A (coop launch unavailable): R8 3-dispatch path.
// ===========================================================================
__global__ __launch_bounds__(PTPB) void prep(const float* __restrict__ x,
                                             const float* __restrict__ W_rel,
                                             const float* __restrict__ W_root,
                                             const float* __restrict__ b_rel,
                                             ushort* __restrict__ y16,
                                             float* __restrict__ out,
                                             const int* __restrict__ ei,
                                             const float* __restrict__ ew,
                                             int* __restrict__ cnt,
                                             int2* __restrict__ pairs,
                                             int nNodes, int nTiles, int E) {
    __shared__ __align__(16) char smem[3 * 65 * 68 * 4];
    const int bid = blockIdx.x;
    const int s3 = bid / 3, r3 = bid - s3 * 3;
    const int tid = threadIdx.x;

    if (r3 != 2) {
        const int gblk = s3 * 2 + r3;
        const int sub = tid >> 8;
        const int t256 = tid & 255;
        const int tile = gblk * GT + sub;
        float* xsT = (float*)smem + sub * (65 * 68);
        float* ws  = (float*)smem + 2 * (65 * 68);
        const int tx = t256 & 15;
        const int ty = t256 >> 4;
        const long nodeBase = (long)tile * 64;
        const int nValid = (int)min((long)64, (long)nNodes - nodeBase);

        for (int f = tid; f < HID * IN_CH; f += PTPB) {
            const int j = f / IN_CH, c = f - j * IN_CH;
            ws[c * 68 + j] = W_rel[f];
        }
        const float* xsrc = x + nodeBase * IN_CH;
        for (int f = t256; f < 64 * IN_CH; f += 256) {
            const int node = f / IN_CH, k = f - node * IN_CH;
            xsT[k * 68 + node] = (node < nValid) ? xsrc[f] : 0.f;
        }
        __syncthreads();

        const int r0 = ty * 4;
        const int c0 = tx * 4;
        {
            float acc[4][4];
#pragma unroll
            for (int i = 0; i < 4; ++i)
#pragma unroll
                for (int j = 0; j < 4; ++j) acc[i][j] = 0.f;
            for (int k = 0; k < IN_CH; ++k) {
                const float4 a4 = *(const float4*)&xsT[k * 68 + r0];
                const float4 b4 = *(const float4*)&ws[k * 68 + c0];
                const float aa[4] = {a4.x, a4.y, a4.z, a4.w};
                const float bb[4] = {b4.x, b4.y, b4.z, b4.w};
#pragma unroll
                for (int i = 0; i < 4; ++i)
#pragma unroll
                    for (int j = 0; j < 4; ++j) acc[i][j] += aa[i] * bb[j];
            }
#pragma unroll
            for (int i = 0; i < 4; ++i) {
                const long node = nodeBase + r0 + i;
                if (node >= nNodes) break;
                uint2 pk;
                pk.x = (uint)f2bf(acc[i][0]) | ((uint)f2bf(acc[i][1]) << 16);
                pk.y = (uint)f2bf(acc[i][2]) | ((uint)f2bf(acc[i][3]) << 16);
                *(uint2*)&y16[node * HID + c0] = pk;
            }
        }
        __syncthreads();
        for (int f = tid; f < HID * IN_CH; f += PTPB) {
            const int j = f / IN_CH, c = f - j * IN_CH;
            ws[c * 68 + j] = W_root[f];
        }
        __syncthreads();
        {
            const float4 bb4 = *(const float4*)&b_rel[c0];
            float acc[4][4];
#pragma unroll
            for (int i = 0; i < 4; ++i) {
                acc[i][0] = bb4.x; acc[i][1] = bb4.y;
                acc[i][2] = bb4.z; acc[i][3] = bb4.w;
            }
            for (int k = 0; k < IN_CH; ++k) {
                const float4 a4 = *(const float4*)&xsT[k * 68 + r0];
                const float4 b4 = *(const float4*)&ws[k * 68 + c0];
                const float aa[4] = {a4.x, a4.y, a4.z, a4.w};
                const float bb[4] = {b4.x, b4.y, b4.z, b4.w};
#pragma unroll
                for (int i = 0; i < 4; ++i)
#pragma unroll
                    for (int j = 0; j < 4; ++j) acc[i][j] += aa[i] * bb[j];
            }
#pragma unroll
            for (int i = 0; i < 4; ++i) {
                const long node = nodeBase + r0 + i;
                if (node >= nNodes) break;
                *(float4*)&out[node * HID + c0] =
                    make_float4(acc[i][0], acc[i][1], acc[i][2], acc[i][3]);
            }
        }
    } else {
        int* lhist = (int*)smem;
        int* lbase = lhist + NB;
        const long e0 = (long)s3 * SEPB;
        const int n = (int)min((long)SEPB, (long)E - e0);

        for (int i = tid; i < NB; i += PTPB) lhist[i] = 0;
        __syncthreads();

        int dstv[SEPT], srcv[SEPT];
        float wv[SEPT];
#pragma unroll
        for (int k = 0; k < SEPT; ++k) {
            const int i = tid + k * PTPB;
            const bool valid = i < n;
            dstv[k] = valid ? ei[(long)E + e0 + i] : 0;
            srcv[k] = valid ? ei[e0 + i] : 0;
            wv[k]   = valid ? ew[e0 + i] : 0.f;
            if (valid) atomicAdd(&lhist[dstv[k] >> 6], 1);
        }
        __syncthreads();

        for (int i = tid; i < NB; i += PTPB) {
            const int c = lhist[i];
            lbase[i] = c ? atomicAdd(&cnt[i], c) : 0;
            lhist[i] = 0;
        }
        __syncthreads();

#pragma unroll
        for (int k = 0; k < SEPT; ++k) {
            const int i = tid + k * PTPB;
            if (i < n) {
                const int b = dstv[k] >> 6;
                const int p = lbase[b] + atomicAdd(&lhist[b], 1);
                if (p < CAP)
                    pairs[(size_t)b * CAP + p] =
                        make_int2((srcv[k] << 7) | ((dstv[k] & (BN - 1)) << 25),
                                  __float_as_int(wv[k]));
            }
        }
    }
}

__global__ __launch_bounds__(512) void aggregateS16(const int2* __restrict__ pairs,
                                                    const int* __restrict__ cnt,
                                                    const ushort* __restrict__ y16,
                                                    float* __restrict__ out, int N) {
    __shared__ int2 sorted[SCAP];
    __shared__ int sH[BN];
    __shared__ int soff[BN + 1];
    __shared__ int scur[BN];
    const int tid = threadIdx.x;
    const int lane = tid & 63;
    const int wvid = tid >> 6;
    const int half = lane >> 5;
    const uint lane4 = (lane & 31) * 4;
    const int b = blockIdx.x;

    if (tid < BN) { sH[tid] = 0; scur[tid] = 0; }

    const int m = min(cnt[b], CAP);
    const int2* pb = pairs + (size_t)b * CAP;

    int2 pv[5];
#pragma unroll
    for (int kk = 0; kk < 5; ++kk) {
        const int i = tid + kk * 512;
        if (i < m) pv[kk] = pb[i];
    }
    __syncthreads();

#pragma unroll
    for (int kk = 0; kk < 5; ++kk) {
        const int i = tid + kk * 512;
        if (i < m) atomicAdd(&sH[(uint)pv[kk].x >> 25], 1);
    }
    __syncthreads();

    for (int off = 1; off < BN; off <<= 1) {
        int v = 0;
        if (tid < BN) {
            v = sH[tid];
            if (tid >= off) v += sH[tid - off];
        }
        __syncthreads();
        if (tid < BN) sH[tid] = v;
        __syncthreads();
    }
    if (tid < BN) soff[tid + 1] = sH[tid];
    if (tid == 0) soff[0] = 0;
    __syncthreads();

#pragma unroll
    for (int kk = 0; kk < 5; ++kk) {
        const int i = tid + kk * 512;
        if (i < m) {
            const int d = (uint)pv[kk].x >> 25;
            const int slot = soff[d] + atomicAdd(&scur[d], 1);
            if (slot < SCAP) sorted[slot] = make_int2(pv[kk].x & 0x00FFFF80, pv[kk].y);
        }
    }
    __syncthreads();

    const char* yb = (const char*)y16;
    const long nodeBase = (long)b * BN;
    for (int nl = wvid; nl < BN; nl += 8) {
        const long node = nodeBase + nl;
        if (node >= N) break;
        const int kbeg = min(soff[nl], SCAP);
        const int kend = min(soff[nl + 1], SCAP);
        float2* o = (float2*)(out + node * HID) + (lane & 31);
        const float2 cur = *o;
        float ax = 0.f, ay = 0.f;
        int k = kbeg + half;
        for (; k + 14 < kend; k += 16) {
            int2 pp[8];
#pragma unroll
            for (int j = 0; j < 8; ++j) pp[j] = sorted[k + 2 * j];
            uint qq[8];
#pragma unroll
            for (int j = 0; j < 8; ++j)
                qq[j] = *(const uint*)(yb + (uint)pp[j].x + lane4);
#pragma unroll
            for (int j = 0; j < 8; ++j) {
                const float w = __int_as_float(pp[j].y);
                ax += w * __uint_as_float(qq[j] << 16);
                ay += w * __uint_as_float(qq[j] & 0xFFFF0000u);
            }
        }
        for (; k + 6 < kend; k += 8) {
            const int2 p0 = sorted[k],     p1 = sorted[k + 2];
            const int2 p2 = sorted[k + 4], p3 = sorted[k + 6];
            const uint q0 = *(const uint*)(yb + (uint)p0.x + lane4);
            const uint q1 = *(const uint*)(yb + (uint)p1.x + lane4);
            const uint q2 = *(const uint*)(yb + (uint)p2.x + lane4);
            const uint q3 = *(const uint*)(yb + (uint)p3.x + lane4);
            const float w0 = __int_as_float(p0.y), w1 = __int_as_float(p1.y);
            const float w2 = __int_as_float(p2.y), w3 = __int_as_float(p3.y);
            ax += w0 * __uint_as_float(q0 << 16);
            ay += w0 * __uint_as_float(q0 & 0xFFFF0000u);
            ax += w1 * __uint_as_float(q1 << 16);
            ay += w1 * __uint_as_float(q1 & 0xFFFF0000u);
            ax += w2 * __uint_as_float(q2 << 16);
            ay += w2 * __uint_as_float(q2 & 0xFFFF0000u);
            ax += w3 * __uint_as_float(q3 << 16);
            ay += w3 * __uint_as_float(q3 & 0xFFFF0000u);
        }
        for (; k < kend; k += 2) {
            const int2 p = sorted[k];
            const uint q = *(const uint*)(yb + (uint)p.x + lane4);
            const float w = __int_as_float(p.y);
            ax += w * __uint_as_float(q << 16);
            ay += w * __uint_as_float(q & 0xFFFF0000u);
        }
        ax += __shfl_xor(ax, 32);
        ay += __shfl_xor(ay, 32);
        if (half == 0) {
            *o = make_float2(cur.x + ax, cur.y + ay);
        }
    }
}

// ===========================================================================
// Fallback B (shape gate fails): original full k1 + atomic scatter.
// ===========================================================================
__global__ __launch_bounds__(256) void k1_full(const float* __restrict__ x,
                                               const float* __restrict__ W_rel,
                                               const float* __restrict__ b_rel,
                                               const float* __restrict__ W_root,
                                               ushort* __restrict__ y16,
                                               float* __restrict__ out,
                                               int nNodes) {
    __shared__ float xs[64 * IN_CH];
    __shared__ float ws[IN_CH * WSTR];
    const int tid = threadIdx.x;
    const int tx = tid & 15;
    const int ty = tid >> 4;
    const long nodeBase = (long)blockIdx.x * 64;
    const int nValid = min(64, nNodes - (int)nodeBase);
    const int nx = nValid * IN_CH;

    for (int f = tid; f < HID * IN_CH; f += 256) {
        const int j = f / IN_CH, c = f - j * IN_CH;
        ws[c * WSTR + j] = W_rel[f];
    }
    for (int f = tid; f < HID * IN_CH; f += 256) {
        const int j = f / IN_CH, c = f - j * IN_CH;
        ws[c * WSTR + HID + j] = W_root[f];
    }
    const float* xsrc = x + nodeBase * IN_CH;
    for (int i = tid; i < 64 * IN_CH; i += 256) xs[i] = (i < nx) ? xsrc[i] : 0.f;
    __syncthreads();

    float acc[4][8];
#pragma unroll
    for (int i = 0; i < 4; ++i)
#pragma unroll
        for (int j = 0; j < 8; ++j) acc[i][j] = 0.f;

    const int r0 = ty * 4;
    const int c0 = tx * 8;
    for (int k = 0; k < IN_CH; ++k) {
        float aa[4] = {xs[(r0 + 0) * IN_CH + k], xs[(r0 + 1) * IN_CH + k],
                       xs[(r0 + 2) * IN_CH + k], xs[(r0 + 3) * IN_CH + k]};
        float4 b0 = *(const float4*)&ws[k * WSTR + c0];
        float4 b1 = *(const float4*)&ws[k * WSTR + c0 + 4];
        float bb[8] = {b0.x, b0.y, b0.z, b0.w, b1.x, b1.y, b1.z, b1.w};
#pragma unroll
        for (int i = 0; i < 4; ++i)
#pragma unroll
            for (int j = 0; j < 8; ++j) acc[i][j] += aa[i] * bb[j];
    }

    if (c0 >= HID) {
        const int h0 = c0 - HID;
        float4 bb0 = *(const float4*)&b_rel[h0];
        float4 bb1 = *(const float4*)&b_rel[h0 + 4];
        float bv[8] = {bb0.x, bb0.y, bb0.z, bb0.w, bb1.x, bb1.y, bb1.z, bb1.w};
#pragma unroll
        for (int i = 0; i < 4; ++i)
#pragma unroll
            for (int j = 0; j < 8; ++j) acc[i][j] += bv[j];
    }

#pragma unroll
    for (int i = 0; i < 4; ++i) {
        const long node = nodeBase + r0 + i;
        if (node >= nNodes) break;
        if (c0 < HID) {
            uint4 pk;
            pk.x = (uint)f2bf(acc[i][0]) | ((uint)f2bf(acc[i][1]) << 16);
            pk.y = (uint)f2bf(acc[i][2]) | ((uint)f2bf(acc[i][3]) << 16);
            pk.z = (uint)f2bf(acc[i][4]) | ((uint)f2bf(acc[i][5]) << 16);
            pk.w = (uint)f2bf(acc[i][6]) | ((uint)f2bf(acc[i][7]) << 16);
            *(uint4*)&y16[node * HID + c0] = pk;
        } else {
            float* dst = out + node * HID + (c0 - HID);
            *(float4*)(dst + 0) = make_float4(acc[i][0], acc[i][1], acc[i][2], acc[i][3]);
            *(float4*)(dst + 4) = make_float4(acc[i][4], acc[i][5], acc[i][6], acc[i][7]);
        }
    }
}

__global__ __launch_bounds__(256) void k2_atomic16(const int* __restrict__ ei,
                                                   const float* __restrict__ ew,
                                                   const ushort* __restrict__ y16,
                                                   float* __restrict__ out, int E) {
    const long t = (long)blockIdx.x * 256 + threadIdx.x;
    const long e = t >> 4;
    const int r = (int)(t & 15);
    if (e >= E) return;
    const int src = ei[e];
    const int dst = ei[(long)E + e];
    const float w = ew[e];
    const uint2 q = ((const uint2*)y16)[(size_t)src * 16 + r];
    float* o = out + (size_t)dst * HID + r * 4;
    unsafeAtomicAdd(o + 0, w * __uint_as_float(q.x << 16));
    unsafeAtomicAdd(o + 1, w * __uint_as_float(q.x & 0xFFFF0000u));
    unsafeAtomicAdd(o + 2, w * __uint_as_float(q.y << 16));
    unsafeAtomicAdd(o + 3, w * __uint_as_float(q.y & 0xFFFF0000u));
}

extern "C" void kernel_launch(void* const* d_in, const int* in_sizes, int n_in,
                              void* d_out, int out_size, void* d_ws, size_t ws_size,
                              hipStream_t stream) {
    const float* x      = (const float*)d_in[0];
    const int*   ei     = (const int*)d_in[1];
    const float* ew     = (const float*)d_in[2];
    const float* W_rel  = (const float*)d_in[3];
    const float* b_rel  = (const float*)d_in[4];
    const float* W_root = (const float*)d_in[5];
    float* out = (float*)d_out;

    const int N = in_sizes[0] / IN_CH;  // 100000
    const int E = in_sizes[2];          // 3200000

    char* base = (char*)d_ws;
    const size_t oY     = 0;
    const size_t oPairs = align16((size_t)N * HID * 2);
    const size_t oCnt   = oPairs + align16((size_t)NB * CAP * 8);
    const size_t need   = oCnt + (size_t)NB * 4;

    ushort* y16 = (ushort*)(base + oY);
    const int nTiles = (N + 63) / 64;

    const bool fits = (ws_size >= need) && (N <= (1 << 17)) &&
                      ((size_t)NB * BN >= (size_t)N) && ((long)E <= (long)N * 33);

    if (fits) {
        int2* pairs = (int2*)(base + oPairs);
        int*  cnt   = (int*)(base + oCnt);

        const int sUnits = (E + SEPB - 1) / SEPB;              // 391
        const int gUnits = (nTiles + GT - 1) / GT;             // 782
        const int nTrip = max((gUnits + 1) / 2, sUnits);       // 391
        const int NU = nTrip * 3;                              // 1173

        // cooperative-launch capability probe (cached; host-side only)
        static int coopGrid = -2;
        if (coopGrid == -2) {
            coopGrid = -1;
            hipDeviceProp_t prop;
            int occ = 0;
            if (hipGetDeviceProperties(&prop, 0) == hipSuccess &&
                prop.cooperativeLaunch &&
                hipOccupancyMaxActiveBlocksPerMultiprocessor(
                    &occ, fused, PTPB, 0) == hipSuccess && occ >= 1) {
                coopGrid = occ * prop.multiProcessorCount;
                if (coopGrid > 768) coopGrid = 768;  // 3/CU target
            }
        }

        bool launched = false;
        if (coopGrid >= 256) {
            const float* xv = x; const float* wrv = W_rel;
            const float* wov = W_root; const float* brv = b_rel;
            ushort* yv = y16; float* ov = out;
            const int* eiv = ei; const float* ewv = ew;
            int* cntv = cnt; int2* pv = pairs;
            int Nv = N, nTv = nTiles, Ev = E, NUv = NU;
            void* kargs[] = {&xv, &wrv, &wov, &brv, &yv, &ov,
                             &eiv, &ewv, &cntv, &pv, &Nv, &nTv, &Ev, &NUv};
            launched = (hipLaunchCooperativeKernel((const void*)fused,
                                                   dim3(coopGrid), dim3(PTPB),
                                                   kargs, 0, stream) == hipSuccess);
        }

        if (!launched) {
            // R8 3-dispatch path (measured 226 us total)
            hipMemsetAsync(cnt, 0, (size_t)NB * sizeof(int), stream);
            const int grid = nTrip * 3;
            prep<<<grid, PTPB, 0, stream>>>(x, W_rel, W_root, b_rel, y16, out,
                                            ei, ew, cnt, pairs, N, nTiles, E);
            aggregateS16<<<NB, 512, 0, stream>>>(pairs, cnt, y16, out, N);
        }
    } else {
        const int nbf = (N + 63) / 64;
        k1_full<<<nbf, 256, 0, stream>>>(x, W_rel, b_rel, W_root, y16, out, N);
        const long thr2 = (long)E * 16;
        k2_atomic16<<<(int)((thr2 + 255) / 256), 256, 0, stream>>>(ei, ew, y16, out, E);
    }
}